// Round 11
// baseline (1225.586 us; speedup 1.0000x reference)
//
#include <hip/hip_runtime.h>
#include <hip/hip_bf16.h>
#include <math.h>

// GCN forward: softmax( A * relu(A*(x@W1)+b1) @ W2 )
// N=100000 nodes, E=3.2M edges, F 512->256->40.
// CSR (dst-sorted) -> gather SpMM. support1 in FP16 (51 MB).
// conv1/conv2: PERSISTENT WAVES (grid-stride over nodes) to remove block
// dispatch churn + tail (occupancy 65% -> target ~90%).
// gemm1: single-buffered fp16 MFMA (r8 proven; double-buffer regressed).
// conv2 gathers fp16-packed c2 (8 MB, L2-resident).

#define NFEAT 512
#define NHID  256
#define NCLASS 40

typedef _Float16 f16x8 __attribute__((ext_vector_type(8)));
typedef float    f32x4 __attribute__((ext_vector_type(4)));

static __device__ __forceinline__ ushort f2h(float f) {
    _Float16 h = (_Float16)f;            // RNE
    ushort u; __builtin_memcpy(&u, &h, 2);
    return u;
}
static __device__ __forceinline__ float h2f(ushort u) {
    _Float16 h; __builtin_memcpy(&h, &u, 2);
    return (float)h;
}
static __device__ __forceinline__ float hlo(unsigned u) { return h2f((ushort)(u & 0xffff)); }
static __device__ __forceinline__ float hhi(unsigned u) { return h2f((ushort)(u >> 16)); }

static __device__ __forceinline__ uint4 pack8(float4 lo, float4 hi) {
    uint4 o;
    o.x = (unsigned)f2h(lo.x) | ((unsigned)f2h(lo.y) << 16);
    o.y = (unsigned)f2h(lo.z) | ((unsigned)f2h(lo.w) << 16);
    o.z = (unsigned)f2h(hi.x) | ((unsigned)f2h(hi.y) << 16);
    o.w = (unsigned)f2h(hi.z) | ((unsigned)f2h(hi.w) << 16);
    return o;
}

// ---------------- W1 -> W1T fp16  ([512][256] -> [256][512]) ----------------
__global__ __launch_bounds__(256) void convert_w1t_kernel(const float* __restrict__ W1,
                                                          ushort* __restrict__ w1t) {
    int k = blockIdx.x;      // 0..511
    int n = threadIdx.x;     // 0..255
    w1t[(size_t)n * NFEAT + k] = f2h(W1[(size_t)k * NHID + n]);
}

// ---------------- W2 transpose: W2T[40][256] <- W2[256][40] (f32) ----------------
__global__ __launch_bounds__(256) void transpose_w2_kernel(const float* __restrict__ W2,
                                                           float* __restrict__ W2T) {
    for (int i = threadIdx.x; i < NHID * NCLASS; i += 256) {
        int k = i / NCLASS, j = i - k * NCLASS;
        W2T[(size_t)j * NHID + k] = W2[i];
    }
}

// ---------------- gemm1 (MFMA fp16, single-buffered r8 form) ----------------
#define GM_BM 128
#define GM_BK 32

__global__ __launch_bounds__(256) void gemm1_mfma_kernel(const float* __restrict__ A,
                                                         const ushort* __restrict__ Bt,
                                                         ushort* __restrict__ Ch,
                                                         int M) {
    __shared__ ushort As[GM_BM * GM_BK];   // 8 KB, XOR-swizzled 16B slots
    __shared__ ushort Bs[GM_BM * GM_BK];   // 8 KB
    const int tid = threadIdx.x;
    const int wid = tid >> 6, lane = tid & 63;
    const int row0 = blockIdx.x * GM_BM;
    const int col0 = blockIdx.y * GM_BM;   // 0 or 128 (N=256)
    const int wr = (wid >> 1) * 64;
    const int wc = (wid & 1) * 64;
    const int l15 = lane & 15;
    const int lq  = lane >> 4;             // k-chunk 0..3

    const int sr = tid >> 2;               // staging row 0..63
    const int sc = tid & 3;                // staging 16B slot (8 fp16 / 32B f32)

    f32x4 acc[4][4] = {};

    for (int k0 = 0; k0 < NFEAT; k0 += GM_BK) {
        {
            int r0g = row0 + sr;
            int r1g = row0 + sr + 64;
            uint4 a0 = make_uint4(0, 0, 0, 0), a1 = make_uint4(0, 0, 0, 0);
            if (r0g < M) {
                const float4* p = reinterpret_cast<const float4*>(&A[(size_t)r0g * NFEAT + k0 + sc * 8]);
                a0 = pack8(p[0], p[1]);
            }
            if (r1g < M) {
                const float4* p = reinterpret_cast<const float4*>(&A[(size_t)r1g * NFEAT + k0 + sc * 8]);
                a1 = pack8(p[0], p[1]);
            }
            int sw0 = sc ^ ((sr ^ (sr >> 2)) & 3);
            int sw1 = sc ^ (((sr + 64) ^ ((sr + 64) >> 2)) & 3);
            *reinterpret_cast<uint4*>(&As[sr * GM_BK + sw0 * 8]) = a0;
            *reinterpret_cast<uint4*>(&As[(sr + 64) * GM_BK + sw1 * 8]) = a1;
            uint4 b0 = *reinterpret_cast<const uint4*>(&Bt[(size_t)(col0 + sr) * NFEAT + k0 + sc * 8]);
            uint4 b1v = *reinterpret_cast<const uint4*>(&Bt[(size_t)(col0 + sr + 64) * NFEAT + k0 + sc * 8]);
            *reinterpret_cast<uint4*>(&Bs[sr * GM_BK + sw0 * 8]) = b0;
            *reinterpret_cast<uint4*>(&Bs[(sr + 64) * GM_BK + sw1 * 8]) = b1v;
        }
        __syncthreads();
        f16x8 af[4], bfr[4];
        #pragma unroll
        for (int mi = 0; mi < 4; ++mi) {
            int r = wr + mi * 16 + l15;
            int sw = lq ^ ((r ^ (r >> 2)) & 3);
            af[mi] = *reinterpret_cast<const f16x8*>(&As[r * GM_BK + sw * 8]);
        }
        #pragma unroll
        for (int ni = 0; ni < 4; ++ni) {
            int c = wc + ni * 16 + l15;
            int sw = lq ^ ((c ^ (c >> 2)) & 3);
            bfr[ni] = *reinterpret_cast<const f16x8*>(&Bs[c * GM_BK + sw * 8]);
        }
        #pragma unroll
        for (int mi = 0; mi < 4; ++mi)
            #pragma unroll
            for (int ni = 0; ni < 4; ++ni)
                acc[mi][ni] = __builtin_amdgcn_mfma_f32_16x16x32_f16(af[mi], bfr[ni], acc[mi][ni], 0, 0, 0);
        __syncthreads();
    }
    // C/D layout: col = lane&15, row = (lane>>4)*4 + reg
    #pragma unroll
    for (int mi = 0; mi < 4; ++mi) {
        #pragma unroll
        for (int j = 0; j < 4; ++j) {
            int gr = row0 + wr + mi * 16 + lq * 4 + j;
            if (gr < M) {
                #pragma unroll
                for (int ni = 0; ni < 4; ++ni) {
                    Ch[(size_t)gr * NHID + col0 + wc + ni * 16 + l15] = f2h(acc[mi][ni][j]);
                }
            }
        }
    }
}

// ---------------- CSR build ----------------
__global__ __launch_bounds__(256) void hist_kernel(const int* __restrict__ dst,
                                                   int* __restrict__ deg, int E2) {
    int i = blockIdx.x * 256 + threadIdx.x;
    if (i < E2) {
        int2 d2 = reinterpret_cast<const int2*>(dst)[i];
        atomicAdd(&deg[d2.x], 1);
        atomicAdd(&deg[d2.y], 1);
    }
}

#define SCAN_CHUNK 1024
__global__ __launch_bounds__(256) void scan1_kernel(const int* __restrict__ deg,
                                                    int* __restrict__ part,
                                                    int* __restrict__ bsums, int N) {
    __shared__ int s[256];
    int b = blockIdx.x, t = threadIdx.x;
    int i0 = b * SCAN_CHUNK + t * 4;
    int d[4];
    #pragma unroll
    for (int u = 0; u < 4; ++u) d[u] = (i0 + u < N) ? deg[i0 + u] : 0;
    int loc = d[0] + d[1] + d[2] + d[3];
    s[t] = loc;
    __syncthreads();
    for (int off = 1; off < 256; off <<= 1) {
        int v = (t >= off) ? s[t - off] : 0;
        __syncthreads();
        s[t] += v;
        __syncthreads();
    }
    int run = s[t] - loc;
    #pragma unroll
    for (int u = 0; u < 4; ++u) {
        if (i0 + u < N) part[i0 + u] = run;
        run += d[u];
    }
    if (t == 255) bsums[b] = s[255];
}

__global__ __launch_bounds__(128) void scan2_kernel(int* __restrict__ bsums, int nb) {
    __shared__ int s[128];
    int t = threadIdx.x;
    int v = (t < nb) ? bsums[t] : 0;
    s[t] = v;
    __syncthreads();
    for (int off = 1; off < 128; off <<= 1) {
        int x = (t >= off) ? s[t - off] : 0;
        __syncthreads();
        s[t] += x;
        __syncthreads();
    }
    if (t < nb) bsums[t] = s[t] - v;
}

__global__ __launch_bounds__(256) void scan3_kernel(int* __restrict__ row_start,
                                                    int* __restrict__ cursor,
                                                    const int* __restrict__ bsums,
                                                    int N, int E) {
    int b = blockIdx.x, t = threadIdx.x;
    int i0 = b * SCAN_CHUNK + t * 4;
    int add = bsums[b];
    #pragma unroll
    for (int u = 0; u < 4; ++u)
        if (i0 + u < N) {
            int v = row_start[i0 + u] + add;
            row_start[i0 + u] = v;
            cursor[i0 + u] = v;
        }
    if (b == 0 && t == 0) row_start[N] = E;
}

__global__ __launch_bounds__(256) void scatter_kernel(const int* __restrict__ src,
                                                      const int* __restrict__ dst,
                                                      const float* __restrict__ w,
                                                      int* __restrict__ cursor,
                                                      int2* __restrict__ csr, int E) {
    int e = blockIdx.x * 256 + threadIdx.x;
    if (e >= E) return;
    int d = dst[e];
    int pos = atomicAdd(&cursor[d], 1);
    csr[pos] = make_int2(src[e], __float_as_int(w[e]));
}

// ---------------- conv1: c2h[n] = fp16( relu((A@suph)[n] + b1) @ W2 ) ----------------
// PERSISTENT: one wave handles nodes n, n+NW, ... Lanes 0-31: even edge of
// pair, 32-63: odd. Lane owns 8 contiguous feats (16B). 8 pair-gathers/batch.
__global__ __launch_bounds__(256, 4) void conv1_kernel(const int2* __restrict__ csr,
                                                       const int* __restrict__ row_start,
                                                       const ushort* __restrict__ suph,
                                                       const float* __restrict__ b1,
                                                       const float* __restrict__ w2t,
                                                       uint* __restrict__ c2h, int N) {
    __shared__ float hrow[4][NHID];       // per-wave slice, 4 KB
    const int wave = threadIdx.x >> 6;
    const int lane = threadIdx.x & 63;
    const int half = lane >> 5;
    const int fl   = lane & 31;
    const int wg   = blockIdx.x * 4 + wave;
    const int nw   = gridDim.x * 4;

    for (int n = wg; n < N; n += nw) {
        const int start = row_start[n], end = row_start[n + 1];
        float acc[8] = {};
        for (int c0 = start; c0 < end; c0 += 64) {
            int clen = min(64, end - c0);
            int2 eL = (lane < clen) ? csr[c0 + lane] : make_int2(0, 0);
            int npairs  = (clen + 1) >> 1;
            int npair8  = (npairs + 7) & ~7;
            for (int t = 0; t < npair8; t += 8) {
                float wv[8];
                uint4 v[8];
                #pragma unroll
                for (int u = 0; u < 8; ++u) {
                    int idx = 2 * (t + u) + half;    // <= 63 by construction
                    int sidx = __shfl(eL.x, idx, 64);
                    wv[u]    = __int_as_float(__shfl(eL.y, idx, 64));
                    v[u] = *reinterpret_cast<const uint4*>(&suph[(size_t)sidx * NHID + fl * 8]);
                }
                #pragma unroll
                for (int u = 0; u < 8; ++u) {
                    acc[0] += wv[u] * hlo(v[u].x);
                    acc[1] += wv[u] * hhi(v[u].x);
                    acc[2] += wv[u] * hlo(v[u].y);
                    acc[3] += wv[u] * hhi(v[u].y);
                    acc[4] += wv[u] * hlo(v[u].z);
                    acc[5] += wv[u] * hhi(v[u].z);
                    acc[6] += wv[u] * hlo(v[u].w);
                    acc[7] += wv[u] * hhi(v[u].w);
                }
            }
        }
        #pragma unroll
        for (int i = 0; i < 8; ++i) acc[i] += __shfl_xor(acc[i], 32, 64);
        if (half == 0) {
            float4 ba = *reinterpret_cast<const float4*>(&b1[fl * 8]);
            float4 bb = *reinterpret_cast<const float4*>(&b1[fl * 8 + 4]);
            *reinterpret_cast<float4*>(&hrow[wave][fl * 8]) =
                make_float4(fmaxf(acc[0] + ba.x, 0.f), fmaxf(acc[1] + ba.y, 0.f),
                            fmaxf(acc[2] + ba.z, 0.f), fmaxf(acc[3] + ba.w, 0.f));
            *reinterpret_cast<float4*>(&hrow[wave][fl * 8 + 4]) =
                make_float4(fmaxf(acc[4] + bb.x, 0.f), fmaxf(acc[5] + bb.y, 0.f),
                            fmaxf(acc[6] + bb.z, 0.f), fmaxf(acc[7] + bb.w, 0.f));
        }
        // wave-local epilogue (same wave wrote hrow[wave])
        float p = 0.f;
        if (lane < NCLASS) {
            const float4* wp = reinterpret_cast<const float4*>(&w2t[(size_t)lane * NHID]);
            const float4* hp = reinterpret_cast<const float4*>(&hrow[wave][0]);
            #pragma unroll 8
            for (int k4 = 0; k4 < 64; ++k4) {
                float4 h4 = hp[k4];
                float4 w4 = wp[k4];
                p += h4.x * w4.x + h4.y * w4.y + h4.z * w4.z + h4.w * w4.w;
            }
        }
        // pack classes (2j, 2j+1) into u32 j; lanes 0..19 write
        float pA = __shfl(p, 2 * lane, 64);
        float pB = __shfl(p, 2 * lane + 1, 64);
        if (lane < 20) {
            c2h[(size_t)n * 20 + lane] = (unsigned)f2h(pA) | ((unsigned)f2h(pB) << 16);
        }
    }
}

// ---------------- conv2: out[n] = softmax( (A @ c2)[n] ) ----------------
// PERSISTENT: one wave per node stride; lanes 0..19 own class-pairs (fp16 x2).
__global__ __launch_bounds__(256, 4) void conv2_kernel(const int2* __restrict__ csr,
                                                       const int* __restrict__ row_start,
                                                       const uint* __restrict__ c2h,
                                                       float* __restrict__ out, int N) {
    const int wave = threadIdx.x >> 6;
    const int lane = threadIdx.x & 63;
    const int wg   = blockIdx.x * 4 + wave;
    const int nw   = gridDim.x * 4;
    const bool act = lane < 20;

    for (int n = wg; n < N; n += nw) {
        const int start = row_start[n], end = row_start[n + 1];
        float a0 = 0.f, a1 = 0.f;
        int j = start;
        for (; j + 15 < end; j += 16) {
            int2 ee[16];
            #pragma unroll
            for (int u = 0; u < 16; ++u) ee[u] = csr[j + u];
            unsigned sv[16];
            #pragma unroll
            for (int u = 0; u < 16; ++u)
                sv[u] = act ? c2h[(size_t)ee[u].x * 20 + lane] : 0u;
            #pragma unroll
            for (int u = 0; u < 16; ++u) {
                float w = __int_as_float(ee[u].y);
                a0 += w * hlo(sv[u]);
                a1 += w * hhi(sv[u]);
            }
        }
        for (; j + 3 < end; j += 4) {
            int2 ee[4];
            #pragma unroll
            for (int u = 0; u < 4; ++u) ee[u] = csr[j + u];
            unsigned sv[4];
            #pragma unroll
            for (int u = 0; u < 4; ++u)
                sv[u] = act ? c2h[(size_t)ee[u].x * 20 + lane] : 0u;
            #pragma unroll
            for (int u = 0; u < 4; ++u) {
                float w = __int_as_float(ee[u].y);
                a0 += w * hlo(sv[u]);
                a1 += w * hhi(sv[u]);
            }
        }
        for (; j < end; ++j) {
            int2 e0 = csr[j];
            unsigned sv = act ? c2h[(size_t)e0.x * 20 + lane] : 0u;
            float w = __int_as_float(e0.y);
            a0 += w * hlo(sv);
            a1 += w * hhi(sv);
        }
        // softmax over 40 classes held 2-per-lane on lanes 0..19
        float m = act ? fmaxf(a0, a1) : -INFINITY;
        #pragma unroll
        for (int off = 32; off > 0; off >>= 1) m = fmaxf(m, __shfl_xor(m, off, 64));
        float e0v = act ? expf(a0 - m) : 0.f;
        float e1v = act ? expf(a1 - m) : 0.f;
        float s = e0v + e1v;
        #pragma unroll
        for (int off = 32; off > 0; off >>= 1) s += __shfl_xor(s, off, 64);
        if (act) {
            float inv = 1.0f / s;
            *reinterpret_cast<float2*>(&out[(size_t)n * NCLASS + lane * 2]) =
                make_float2(e0v * inv, e1v * inv);
        }
    }
}

extern "C" void kernel_launch(void* const* d_in, const int* in_sizes, int n_in,
                              void* d_out, int out_size, void* d_ws, size_t ws_size,
                              hipStream_t stream) {
    const float* x  = (const float*)d_in[0];
    const int*   ei = (const int*)d_in[1];
    const float* ew = (const float*)d_in[2];
    const float* W1 = (const float*)d_in[3];
    const float* b1 = (const float*)d_in[4];
    const float* W2 = (const float*)d_in[5];
    float* out = (float*)d_out;

    const int M = in_sizes[0] / NFEAT;       // 100000
    const int E = in_sizes[1] / 2;           // 3200000
    const int* src = ei;
    const int* dst = ei + E;

    // workspace layout (~86 MB)
    char* ws = (char*)d_ws;
    ushort* suph    = (ushort*)ws;                                  // M*256 fp16 = 51.2 MB
    uint*   c2h     = (uint*)(suph + (size_t)M * NHID);             // M*20 u32   = 8 MB
    int2*   csr     = (int2*)(c2h + (size_t)M * 20);                // E int2     = 25.6 MB
    int*    deg     = (int*)(csr + E);                              // M
    int*    row_start = deg + M;                                    // M+1
    int*    cursor  = row_start + (M + 1);                          // M
    int*    bsums   = cursor + M;                                   // 128
    float*  w2t     = (float*)(bsums + 128);                        // 40*256 f32
    ushort* w1t     = (ushort*)(w2t + NCLASS * NHID);               // 256*512 fp16

    const int nscan = (M + SCAN_CHUNK - 1) / SCAN_CHUNK;

    // ---- converts + CSR build ----
    convert_w1t_kernel<<<NFEAT, 256, 0, stream>>>(W1, w1t);
    transpose_w2_kernel<<<1, 256, 0, stream>>>(W2, w2t);

    hipMemsetAsync(deg, 0, (size_t)M * 4, stream);
    hist_kernel<<<(E / 2 + 255) / 256, 256, 0, stream>>>(dst, deg, E / 2);
    scan1_kernel<<<nscan, 256, 0, stream>>>(deg, row_start, bsums, M);
    scan2_kernel<<<1, 128, 0, stream>>>(bsums, nscan);
    scan3_kernel<<<nscan, 256, 0, stream>>>(row_start, cursor, bsums, M, E);
    scatter_kernel<<<(E + 255) / 256, 256, 0, stream>>>(src, dst, ew, cursor, csr, E);

    // ---- dense + sparse pipeline ----
    dim3 g1((M + GM_BM - 1) / GM_BM, NHID / GM_BM);
    gemm1_mfma_kernel<<<g1, 256, 0, stream>>>(x, w1t, suph, M);

    conv1_kernel<<<2048, 256, 0, stream>>>(csr, row_start, suph, b1, w2t, c2h, M);
    conv2_kernel<<<2048, 256, 0, stream>>>(csr, row_start, c2h, out, M);
}

// Round 12
// 1207.484 us; speedup vs baseline: 1.0150x; 1.0150x over previous
//
#include <hip/hip_runtime.h>
#include <hip/hip_bf16.h>
#include <math.h>

// GCN forward: softmax( A * relu(A*(x@W1)+b1) @ W2 )
// N=100000 nodes, E=3.2M edges, F 512->256->40.
// CSR (dst-sorted) -> gather SpMM. support1 in FP16 (51 MB).
// conv1: wave-per-node 8-deep gather -- EMPIRICAL PLATEAU ~615us across 7
// structural variants (ILP 2-16 deep, persistent, fences): row-gather-rate
// bound (~5G rows/s). Do not touch.
// conv2: f32 c2, 40 active lanes, 16-deep (r8-proven; fp16-c2h regressed).
// gemm1: fp16 MFMA, BN=256 (stage A once for ALL cols -> x read once).

#define NFEAT 512
#define NHID  256
#define NCLASS 40

typedef _Float16 f16x8 __attribute__((ext_vector_type(8)));
typedef float    f32x4 __attribute__((ext_vector_type(4)));

static __device__ __forceinline__ ushort f2h(float f) {
    _Float16 h = (_Float16)f;            // RNE
    ushort u; __builtin_memcpy(&u, &h, 2);
    return u;
}
static __device__ __forceinline__ float h2f(ushort u) {
    _Float16 h; __builtin_memcpy(&h, &u, 2);
    return (float)h;
}
static __device__ __forceinline__ float hlo(unsigned u) { return h2f((ushort)(u & 0xffff)); }
static __device__ __forceinline__ float hhi(unsigned u) { return h2f((ushort)(u >> 16)); }

static __device__ __forceinline__ uint4 pack8(float4 lo, float4 hi) {
    uint4 o;
    o.x = (unsigned)f2h(lo.x) | ((unsigned)f2h(lo.y) << 16);
    o.y = (unsigned)f2h(lo.z) | ((unsigned)f2h(lo.w) << 16);
    o.z = (unsigned)f2h(hi.x) | ((unsigned)f2h(hi.y) << 16);
    o.w = (unsigned)f2h(hi.z) | ((unsigned)f2h(hi.w) << 16);
    return o;
}

// ---------------- W1 -> W1T fp16  ([512][256] -> [256][512]) ----------------
__global__ __launch_bounds__(256) void convert_w1t_kernel(const float* __restrict__ W1,
                                                          ushort* __restrict__ w1t) {
    int k = blockIdx.x;      // 0..511
    int n = threadIdx.x;     // 0..255
    w1t[(size_t)n * NFEAT + k] = f2h(W1[(size_t)k * NHID + n]);
}

// ---------------- W2 transpose: W2T[40][256] <- W2[256][40] (f32) ----------------
__global__ __launch_bounds__(256) void transpose_w2_kernel(const float* __restrict__ W2,
                                                           float* __restrict__ W2T) {
    for (int i = threadIdx.x; i < NHID * NCLASS; i += 256) {
        int k = i / NCLASS, j = i - k * NCLASS;
        W2T[(size_t)j * NHID + k] = W2[i];
    }
}

// ---------------- gemm1 (MFMA fp16): suph = fp16( x @ W1 ) ----------------
// 128x256 tile (full N in one block -> x staged/read ONCE), BK=32, 4 waves
// (2x2), each wave 64x128 via 4x8 16x16x32 frags.
#define GM_BM 128
#define GM_BK 32

__global__ __launch_bounds__(256) void gemm1_mfma_kernel(const float* __restrict__ A,
                                                         const ushort* __restrict__ Bt,
                                                         ushort* __restrict__ Ch,
                                                         int M) {
    __shared__ ushort As[GM_BM * GM_BK];   // 8 KB, XOR-swizzled 16B slots
    __shared__ ushort Bs[NHID * GM_BK];    // 16 KB (all 256 cols)
    const int tid = threadIdx.x;
    const int wid = tid >> 6, lane = tid & 63;
    const int row0 = blockIdx.x * GM_BM;
    const int wr = (wid >> 1) * 64;        // wave row 0 or 64
    const int wc = (wid & 1) * 128;        // wave col 0 or 128
    const int l15 = lane & 15;
    const int lq  = lane >> 4;             // k-chunk 0..3

    const int sr = tid >> 2;               // staging row 0..63
    const int sc = tid & 3;                // staging 16B slot (8 fp16 / 32B f32)

    f32x4 acc[4][8] = {};

    for (int k0 = 0; k0 < NFEAT; k0 += GM_BK) {
        {
            int r0g = row0 + sr;
            int r1g = row0 + sr + 64;
            uint4 a0 = make_uint4(0, 0, 0, 0), a1 = make_uint4(0, 0, 0, 0);
            if (r0g < M) {
                const float4* p = reinterpret_cast<const float4*>(&A[(size_t)r0g * NFEAT + k0 + sc * 8]);
                a0 = pack8(p[0], p[1]);
            }
            if (r1g < M) {
                const float4* p = reinterpret_cast<const float4*>(&A[(size_t)r1g * NFEAT + k0 + sc * 8]);
                a1 = pack8(p[0], p[1]);
            }
            int sw0 = sc ^ ((sr ^ (sr >> 2)) & 3);
            int sw1 = sc ^ (((sr + 64) ^ ((sr + 64) >> 2)) & 3);
            *reinterpret_cast<uint4*>(&As[sr * GM_BK + sw0 * 8]) = a0;
            *reinterpret_cast<uint4*>(&As[(sr + 64) * GM_BK + sw1 * 8]) = a1;
            #pragma unroll
            for (int q = 0; q < 4; ++q) {
                int br = sr + 64 * q;
                uint4 bv = *reinterpret_cast<const uint4*>(&Bt[(size_t)br * NFEAT + k0 + sc * 8]);
                int sw = sc ^ ((br ^ (br >> 2)) & 3);
                *reinterpret_cast<uint4*>(&Bs[br * GM_BK + sw * 8]) = bv;
            }
        }
        __syncthreads();
        f16x8 af[4], bfr[8];
        #pragma unroll
        for (int mi = 0; mi < 4; ++mi) {
            int r = wr + mi * 16 + l15;
            int sw = lq ^ ((r ^ (r >> 2)) & 3);
            af[mi] = *reinterpret_cast<const f16x8*>(&As[r * GM_BK + sw * 8]);
        }
        #pragma unroll
        for (int ni = 0; ni < 8; ++ni) {
            int c = wc + ni * 16 + l15;
            int sw = lq ^ ((c ^ (c >> 2)) & 3);
            bfr[ni] = *reinterpret_cast<const f16x8*>(&Bs[c * GM_BK + sw * 8]);
        }
        #pragma unroll
        for (int mi = 0; mi < 4; ++mi)
            #pragma unroll
            for (int ni = 0; ni < 8; ++ni)
                acc[mi][ni] = __builtin_amdgcn_mfma_f32_16x16x32_f16(af[mi], bfr[ni], acc[mi][ni], 0, 0, 0);
        __syncthreads();
    }
    // C/D layout: col = lane&15, row = (lane>>4)*4 + reg
    #pragma unroll
    for (int mi = 0; mi < 4; ++mi) {
        #pragma unroll
        for (int j = 0; j < 4; ++j) {
            int gr = row0 + wr + mi * 16 + lq * 4 + j;
            if (gr < M) {
                #pragma unroll
                for (int ni = 0; ni < 8; ++ni) {
                    Ch[(size_t)gr * NHID + wc + ni * 16 + l15] = f2h(acc[mi][ni][j]);
                }
            }
        }
    }
}

// ---------------- CSR build ----------------
__global__ __launch_bounds__(256) void hist_kernel(const int* __restrict__ dst,
                                                   int* __restrict__ deg, int E2) {
    int i = blockIdx.x * 256 + threadIdx.x;
    if (i < E2) {
        int2 d2 = reinterpret_cast<const int2*>(dst)[i];
        atomicAdd(&deg[d2.x], 1);
        atomicAdd(&deg[d2.y], 1);
    }
}

#define SCAN_CHUNK 1024
__global__ __launch_bounds__(256) void scan1_kernel(const int* __restrict__ deg,
                                                    int* __restrict__ part,
                                                    int* __restrict__ bsums, int N) {
    __shared__ int s[256];
    int b = blockIdx.x, t = threadIdx.x;
    int i0 = b * SCAN_CHUNK + t * 4;
    int d[4];
    #pragma unroll
    for (int u = 0; u < 4; ++u) d[u] = (i0 + u < N) ? deg[i0 + u] : 0;
    int loc = d[0] + d[1] + d[2] + d[3];
    s[t] = loc;
    __syncthreads();
    for (int off = 1; off < 256; off <<= 1) {
        int v = (t >= off) ? s[t - off] : 0;
        __syncthreads();
        s[t] += v;
        __syncthreads();
    }
    int run = s[t] - loc;
    #pragma unroll
    for (int u = 0; u < 4; ++u) {
        if (i0 + u < N) part[i0 + u] = run;
        run += d[u];
    }
    if (t == 255) bsums[b] = s[255];
}

__global__ __launch_bounds__(128) void scan2_kernel(int* __restrict__ bsums, int nb) {
    __shared__ int s[128];
    int t = threadIdx.x;
    int v = (t < nb) ? bsums[t] : 0;
    s[t] = v;
    __syncthreads();
    for (int off = 1; off < 128; off <<= 1) {
        int x = (t >= off) ? s[t - off] : 0;
        __syncthreads();
        s[t] += x;
        __syncthreads();
    }
    if (t < nb) bsums[t] = s[t] - v;
}

__global__ __launch_bounds__(256) void scan3_kernel(int* __restrict__ row_start,
                                                    int* __restrict__ cursor,
                                                    const int* __restrict__ bsums,
                                                    int N, int E) {
    int b = blockIdx.x, t = threadIdx.x;
    int i0 = b * SCAN_CHUNK + t * 4;
    int add = bsums[b];
    #pragma unroll
    for (int u = 0; u < 4; ++u)
        if (i0 + u < N) {
            int v = row_start[i0 + u] + add;
            row_start[i0 + u] = v;
            cursor[i0 + u] = v;
        }
    if (b == 0 && t == 0) row_start[N] = E;
}

__global__ __launch_bounds__(256) void scatter_kernel(const int* __restrict__ src,
                                                      const int* __restrict__ dst,
                                                      const float* __restrict__ w,
                                                      int* __restrict__ cursor,
                                                      int2* __restrict__ csr, int E) {
    int e = blockIdx.x * 256 + threadIdx.x;
    if (e >= E) return;
    int d = dst[e];
    int pos = atomicAdd(&cursor[d], 1);
    csr[pos] = make_int2(src[e], __float_as_int(w[e]));
}

// ---------------- conv1: c2[n] = relu( (A @ suph)[n] + b1 ) @ W2 ----------------
// ONE WAVE per node (r8 form: empirical best, do not touch). Lanes 0-31: even
// edge of pair, 32-63: odd. Lane owns 8 contiguous feats (16B). 8 gathers/batch.
__global__ __launch_bounds__(256, 4) void conv1_kernel(const int2* __restrict__ csr,
                                                       const int* __restrict__ row_start,
                                                       const ushort* __restrict__ suph,
                                                       const float* __restrict__ b1,
                                                       const float* __restrict__ w2t,
                                                       float* __restrict__ c2, int N) {
    __shared__ float hrow[4][NHID];       // per-wave slice, 4 KB
    const int wave = threadIdx.x >> 6;
    const int lane = threadIdx.x & 63;
    const int half = lane >> 5;
    const int fl   = lane & 31;
    const int n = blockIdx.x * 4 + wave;
    if (n >= N) return;
    const int start = row_start[n], end = row_start[n + 1];

    float acc[8] = {};
    for (int c0 = start; c0 < end; c0 += 64) {
        int clen = min(64, end - c0);
        int2 eL = (lane < clen) ? csr[c0 + lane] : make_int2(0, 0);
        int npairs  = (clen + 1) >> 1;
        int npair8  = (npairs + 7) & ~7;
        for (int t = 0; t < npair8; t += 8) {
            float wv[8];
            uint4 v[8];
            #pragma unroll
            for (int u = 0; u < 8; ++u) {
                int idx = 2 * (t + u) + half;    // <= 63 by construction
                int sidx = __shfl(eL.x, idx, 64);
                wv[u]    = __int_as_float(__shfl(eL.y, idx, 64));
                v[u] = *reinterpret_cast<const uint4*>(&suph[(size_t)sidx * NHID + fl * 8]);
            }
            #pragma unroll
            for (int u = 0; u < 8; ++u) {
                acc[0] += wv[u] * hlo(v[u].x);
                acc[1] += wv[u] * hhi(v[u].x);
                acc[2] += wv[u] * hlo(v[u].y);
                acc[3] += wv[u] * hhi(v[u].y);
                acc[4] += wv[u] * hlo(v[u].z);
                acc[5] += wv[u] * hhi(v[u].z);
                acc[6] += wv[u] * hlo(v[u].w);
                acc[7] += wv[u] * hhi(v[u].w);
            }
        }
    }
    #pragma unroll
    for (int i = 0; i < 8; ++i) acc[i] += __shfl_xor(acc[i], 32, 64);
    if (half == 0) {
        float4 ba = *reinterpret_cast<const float4*>(&b1[fl * 8]);
        float4 bb = *reinterpret_cast<const float4*>(&b1[fl * 8 + 4]);
        *reinterpret_cast<float4*>(&hrow[wave][fl * 8]) =
            make_float4(fmaxf(acc[0] + ba.x, 0.f), fmaxf(acc[1] + ba.y, 0.f),
                        fmaxf(acc[2] + ba.z, 0.f), fmaxf(acc[3] + ba.w, 0.f));
        *reinterpret_cast<float4*>(&hrow[wave][fl * 8 + 4]) =
            make_float4(fmaxf(acc[4] + bb.x, 0.f), fmaxf(acc[5] + bb.y, 0.f),
                        fmaxf(acc[6] + bb.z, 0.f), fmaxf(acc[7] + bb.w, 0.f));
    }
    // wave-local epilogue (same wave wrote hrow[wave])
    if (lane < NCLASS) {
        const float4* wp = reinterpret_cast<const float4*>(&w2t[(size_t)lane * NHID]);
        const float4* hp = reinterpret_cast<const float4*>(&hrow[wave][0]);
        float p = 0.f;
        #pragma unroll 8
        for (int k4 = 0; k4 < 64; ++k4) {
            float4 h4 = hp[k4];
            float4 w4 = wp[k4];
            p += h4.x * w4.x + h4.y * w4.y + h4.z * w4.z + h4.w * w4.w;
        }
        c2[(size_t)n * NCLASS + lane] = p;
    }
}

// ---------------- conv2: out[n] = softmax( (A @ c2)[n] ) ----------------
// one wave per node; lanes 0..39 own classes; 16 edges in flight (r8 form).
__global__ __launch_bounds__(256, 4) void conv2_kernel(const int2* __restrict__ csr,
                                                       const int* __restrict__ row_start,
                                                       const float* __restrict__ c2,
                                                       float* __restrict__ out, int N) {
    int wave = threadIdx.x >> 6;
    int lane = threadIdx.x & 63;
    int n = blockIdx.x * 4 + wave;
    if (n >= N) return;
    int start = row_start[n], end = row_start[n + 1];
    bool act = lane < NCLASS;
    float acc = 0.f;
    int j = start;
    for (; j + 15 < end; j += 16) {
        int2 ee[16];
        #pragma unroll
        for (int u = 0; u < 16; ++u) ee[u] = csr[j + u];
        if (act) {
            float sv[16];
            #pragma unroll
            for (int u = 0; u < 16; ++u) sv[u] = c2[(size_t)ee[u].x * NCLASS + lane];
            #pragma unroll
            for (int u = 0; u < 16; ++u) acc += __int_as_float(ee[u].y) * sv[u];
        }
    }
    for (; j + 3 < end; j += 4) {
        int2 ee[4];
        #pragma unroll
        for (int u = 0; u < 4; ++u) ee[u] = csr[j + u];
        if (act) {
            float sv[4];
            #pragma unroll
            for (int u = 0; u < 4; ++u) sv[u] = c2[(size_t)ee[u].x * NCLASS + lane];
            #pragma unroll
            for (int u = 0; u < 4; ++u) acc += __int_as_float(ee[u].y) * sv[u];
        }
    }
    for (; j < end; ++j) {
        int2 e0 = csr[j];
        if (act) acc += __int_as_float(e0.y) * c2[(size_t)e0.x * NCLASS + lane];
    }
    float m = act ? acc : -INFINITY;
    #pragma unroll
    for (int off = 32; off > 0; off >>= 1) m = fmaxf(m, __shfl_xor(m, off, 64));
    float e = act ? expf(acc - m) : 0.f;
    float s = e;
    #pragma unroll
    for (int off = 32; off > 0; off >>= 1) s += __shfl_xor(s, off, 64);
    if (act) out[(size_t)n * NCLASS + lane] = e / s;
}

extern "C" void kernel_launch(void* const* d_in, const int* in_sizes, int n_in,
                              void* d_out, int out_size, void* d_ws, size_t ws_size,
                              hipStream_t stream) {
    const float* x  = (const float*)d_in[0];
    const int*   ei = (const int*)d_in[1];
    const float* ew = (const float*)d_in[2];
    const float* W1 = (const float*)d_in[3];
    const float* b1 = (const float*)d_in[4];
    const float* W2 = (const float*)d_in[5];
    float* out = (float*)d_out;

    const int M = in_sizes[0] / NFEAT;       // 100000
    const int E = in_sizes[1] / 2;           // 3200000
    const int* src = ei;
    const int* dst = ei + E;

    // workspace layout (~94 MB)
    char* ws = (char*)d_ws;
    ushort* suph    = (ushort*)ws;                                  // M*256 fp16 = 51.2 MB
    float*  c2      = (float*)(suph + (size_t)M * NHID);            // M*40 f32   = 16 MB
    int2*   csr     = (int2*)(c2 + (size_t)M * NCLASS);             // E int2     = 25.6 MB
    int*    deg     = (int*)(csr + E);                              // M
    int*    row_start = deg + M;                                    // M+1
    int*    cursor  = row_start + (M + 1);                          // M
    int*    bsums   = cursor + M;                                   // 128
    float*  w2t     = (float*)(bsums + 128);                        // 40*256 f32
    ushort* w1t     = (ushort*)(w2t + NCLASS * NHID);               // 256*512 fp16

    const int nscan = (M + SCAN_CHUNK - 1) / SCAN_CHUNK;

    // ---- converts + CSR build ----
    convert_w1t_kernel<<<NFEAT, 256, 0, stream>>>(W1, w1t);
    transpose_w2_kernel<<<1, 256, 0, stream>>>(W2, w2t);

    hipMemsetAsync(deg, 0, (size_t)M * 4, stream);
    hist_kernel<<<(E / 2 + 255) / 256, 256, 0, stream>>>(dst, deg, E / 2);
    scan1_kernel<<<nscan, 256, 0, stream>>>(deg, row_start, bsums, M);
    scan2_kernel<<<1, 128, 0, stream>>>(bsums, nscan);
    scan3_kernel<<<nscan, 256, 0, stream>>>(row_start, cursor, bsums, M, E);
    scatter_kernel<<<(E + 255) / 256, 256, 0, stream>>>(src, dst, ew, cursor, csr, E);

    // ---- dense + sparse pipeline ----
    gemm1_mfma_kernel<<<(M + GM_BM - 1) / GM_BM, 256, 0, stream>>>(x, w1t, suph, M);

    conv1_kernel<<<(M + 3) / 4, 256, 0, stream>>>(csr, row_start, suph, b1, w2t, c2, M);
    conv2_kernel<<<(M + 3) / 4, 256, 0, stream>>>(csr, row_start, c2, out, M);
}

// Round 13
// 1151.845 us; speedup vs baseline: 1.0640x; 1.0483x over previous
//
#include <hip/hip_runtime.h>
#include <hip/hip_bf16.h>
#include <math.h>

// GCN forward: softmax( A * relu(A*(x@W1)+b1) @ W2 )
// N=100000 nodes, E=3.2M edges, F 512->256->40.
// CSR (dst-sorted) -> gather SpMM. support1 in FP16 (51 MB).
// conv1: TWO FEATURE-HALF PASSES (working set 25.6 MB/pass -> L2/L3 resident;
// tests residency-bound vs fabric-bound). Partial c2 accumulated across passes
// (relu is elementwise -> epilogue splits cleanly). 4 rows per wave-load.
// conv2: f32 c2, 40 lanes, 16-deep (r8-proven). gemm1: exact r7 128x128 form.

#define NFEAT 512
#define NHID  256
#define NCLASS 40

typedef _Float16 f16x8 __attribute__((ext_vector_type(8)));
typedef float    f32x4 __attribute__((ext_vector_type(4)));

static __device__ __forceinline__ ushort f2h(float f) {
    _Float16 h = (_Float16)f;            // RNE
    ushort u; __builtin_memcpy(&u, &h, 2);
    return u;
}
static __device__ __forceinline__ float h2f(ushort u) {
    _Float16 h; __builtin_memcpy(&h, &u, 2);
    return (float)h;
}
static __device__ __forceinline__ float hlo(unsigned u) { return h2f((ushort)(u & 0xffff)); }
static __device__ __forceinline__ float hhi(unsigned u) { return h2f((ushort)(u >> 16)); }

static __device__ __forceinline__ uint4 pack8(float4 lo, float4 hi) {
    uint4 o;
    o.x = (unsigned)f2h(lo.x) | ((unsigned)f2h(lo.y) << 16);
    o.y = (unsigned)f2h(lo.z) | ((unsigned)f2h(lo.w) << 16);
    o.z = (unsigned)f2h(hi.x) | ((unsigned)f2h(hi.y) << 16);
    o.w = (unsigned)f2h(hi.z) | ((unsigned)f2h(hi.w) << 16);
    return o;
}

// ---------------- W1 -> W1T fp16  ([512][256] -> [256][512]) ----------------
__global__ __launch_bounds__(256) void convert_w1t_kernel(const float* __restrict__ W1,
                                                          ushort* __restrict__ w1t) {
    int k = blockIdx.x;      // 0..511
    int n = threadIdx.x;     // 0..255
    w1t[(size_t)n * NFEAT + k] = f2h(W1[(size_t)k * NHID + n]);
}

// ---------------- W2 transpose: W2T[40][256] <- W2[256][40] (f32) ----------------
__global__ __launch_bounds__(256) void transpose_w2_kernel(const float* __restrict__ W2,
                                                           float* __restrict__ W2T) {
    for (int i = threadIdx.x; i < NHID * NCLASS; i += 256) {
        int k = i / NCLASS, j = i - k * NCLASS;
        W2T[(size_t)j * NHID + k] = W2[i];
    }
}

// ---------------- gemm1 (MFMA fp16, exact r7 form): suph = fp16( x @ W1 ) ----
#define GM_BM 128
#define GM_BK 32

__global__ __launch_bounds__(256) void gemm1_mfma_kernel(const float* __restrict__ A,
                                                         const ushort* __restrict__ Bt,
                                                         ushort* __restrict__ Ch,
                                                         int M) {
    __shared__ ushort As[GM_BM * GM_BK];   // 8 KB, XOR-swizzled 16B slots
    __shared__ ushort Bs[GM_BM * GM_BK];   // 8 KB
    const int tid = threadIdx.x;
    const int wid = tid >> 6, lane = tid & 63;
    const int row0 = blockIdx.x * GM_BM;
    const int col0 = blockIdx.y * GM_BM;   // 0 or 128 (N=256)
    const int wr = (wid >> 1) * 64;
    const int wc = (wid & 1) * 64;
    const int l15 = lane & 15;
    const int lq  = lane >> 4;             // k-chunk 0..3

    const int sr = tid >> 2;               // staging row 0..63
    const int sc = tid & 3;                // staging 16B slot (8 fp16 / 32B f32)

    f32x4 acc[4][4] = {};

    for (int k0 = 0; k0 < NFEAT; k0 += GM_BK) {
        {
            int r0g = row0 + sr;
            int r1g = row0 + sr + 64;
            uint4 a0 = make_uint4(0, 0, 0, 0), a1 = make_uint4(0, 0, 0, 0);
            if (r0g < M) {
                const float4* p = reinterpret_cast<const float4*>(&A[(size_t)r0g * NFEAT + k0 + sc * 8]);
                a0 = pack8(p[0], p[1]);
            }
            if (r1g < M) {
                const float4* p = reinterpret_cast<const float4*>(&A[(size_t)r1g * NFEAT + k0 + sc * 8]);
                a1 = pack8(p[0], p[1]);
            }
            int sw0 = sc ^ ((sr ^ (sr >> 2)) & 3);
            int sw1 = sc ^ (((sr + 64) ^ ((sr + 64) >> 2)) & 3);
            *reinterpret_cast<uint4*>(&As[sr * GM_BK + sw0 * 8]) = a0;
            *reinterpret_cast<uint4*>(&As[(sr + 64) * GM_BK + sw1 * 8]) = a1;
            uint4 b0 = *reinterpret_cast<const uint4*>(&Bt[(size_t)(col0 + sr) * NFEAT + k0 + sc * 8]);
            uint4 b1v = *reinterpret_cast<const uint4*>(&Bt[(size_t)(col0 + sr + 64) * NFEAT + k0 + sc * 8]);
            *reinterpret_cast<uint4*>(&Bs[sr * GM_BK + sw0 * 8]) = b0;
            *reinterpret_cast<uint4*>(&Bs[(sr + 64) * GM_BK + sw1 * 8]) = b1v;
        }
        __syncthreads();
        f16x8 af[4], bfr[4];
        #pragma unroll
        for (int mi = 0; mi < 4; ++mi) {
            int r = wr + mi * 16 + l15;
            int sw = lq ^ ((r ^ (r >> 2)) & 3);
            af[mi] = *reinterpret_cast<const f16x8*>(&As[r * GM_BK + sw * 8]);
        }
        #pragma unroll
        for (int ni = 0; ni < 4; ++ni) {
            int c = wc + ni * 16 + l15;
            int sw = lq ^ ((c ^ (c >> 2)) & 3);
            bfr[ni] = *reinterpret_cast<const f16x8*>(&Bs[c * GM_BK + sw * 8]);
        }
        #pragma unroll
        for (int mi = 0; mi < 4; ++mi)
            #pragma unroll
            for (int ni = 0; ni < 4; ++ni)
                acc[mi][ni] = __builtin_amdgcn_mfma_f32_16x16x32_f16(af[mi], bfr[ni], acc[mi][ni], 0, 0, 0);
        __syncthreads();
    }
    // C/D layout: col = lane&15, row = (lane>>4)*4 + reg
    #pragma unroll
    for (int mi = 0; mi < 4; ++mi) {
        #pragma unroll
        for (int j = 0; j < 4; ++j) {
            int gr = row0 + wr + mi * 16 + lq * 4 + j;
            if (gr < M) {
                #pragma unroll
                for (int ni = 0; ni < 4; ++ni) {
                    Ch[(size_t)gr * NHID + col0 + wc + ni * 16 + l15] = f2h(acc[mi][ni][j]);
                }
            }
        }
    }
}

// ---------------- CSR build ----------------
__global__ __launch_bounds__(256) void hist_kernel(const int* __restrict__ dst,
                                                   int* __restrict__ deg, int E2) {
    int i = blockIdx.x * 256 + threadIdx.x;
    if (i < E2) {
        int2 d2 = reinterpret_cast<const int2*>(dst)[i];
        atomicAdd(&deg[d2.x], 1);
        atomicAdd(&deg[d2.y], 1);
    }
}

#define SCAN_CHUNK 1024
__global__ __launch_bounds__(256) void scan1_kernel(const int* __restrict__ deg,
                                                    int* __restrict__ part,
                                                    int* __restrict__ bsums, int N) {
    __shared__ int s[256];
    int b = blockIdx.x, t = threadIdx.x;
    int i0 = b * SCAN_CHUNK + t * 4;
    int d[4];
    #pragma unroll
    for (int u = 0; u < 4; ++u) d[u] = (i0 + u < N) ? deg[i0 + u] : 0;
    int loc = d[0] + d[1] + d[2] + d[3];
    s[t] = loc;
    __syncthreads();
    for (int off = 1; off < 256; off <<= 1) {
        int v = (t >= off) ? s[t - off] : 0;
        __syncthreads();
        s[t] += v;
        __syncthreads();
    }
    int run = s[t] - loc;
    #pragma unroll
    for (int u = 0; u < 4; ++u) {
        if (i0 + u < N) part[i0 + u] = run;
        run += d[u];
    }
    if (t == 255) bsums[b] = s[255];
}

__global__ __launch_bounds__(128) void scan2_kernel(int* __restrict__ bsums, int nb) {
    __shared__ int s[128];
    int t = threadIdx.x;
    int v = (t < nb) ? bsums[t] : 0;
    s[t] = v;
    __syncthreads();
    for (int off = 1; off < 128; off <<= 1) {
        int x = (t >= off) ? s[t - off] : 0;
        __syncthreads();
        s[t] += x;
        __syncthreads();
    }
    if (t < nb) bsums[t] = s[t] - v;
}

__global__ __launch_bounds__(256) void scan3_kernel(int* __restrict__ row_start,
                                                    int* __restrict__ cursor,
                                                    const int* __restrict__ bsums,
                                                    int N, int E) {
    int b = blockIdx.x, t = threadIdx.x;
    int i0 = b * SCAN_CHUNK + t * 4;
    int add = bsums[b];
    #pragma unroll
    for (int u = 0; u < 4; ++u)
        if (i0 + u < N) {
            int v = row_start[i0 + u] + add;
            row_start[i0 + u] = v;
            cursor[i0 + u] = v;
        }
    if (b == 0 && t == 0) row_start[N] = E;
}

__global__ __launch_bounds__(256) void scatter_kernel(const int* __restrict__ src,
                                                      const int* __restrict__ dst,
                                                      const float* __restrict__ w,
                                                      int* __restrict__ cursor,
                                                      int2* __restrict__ csr, int E) {
    int e = blockIdx.x * 256 + threadIdx.x;
    if (e >= E) return;
    int d = dst[e];
    int pos = atomicAdd(&cursor[d], 1);
    csr[pos] = make_int2(src[e], __float_as_int(w[e]));
}

// ---- conv1 half-pass: c2[n] (+)= relu((A@suph)[n]+b1)[half] @ W2T[:, half] ----
// ONE WAVE per node. 4 edge-rows per wave-load: lane group g = lane>>4 owns
// edge 4q+g, lane fl = lane&15 owns feats half*128 + fl*8 .. +7 (16 B).
// Working set per pass = 25.6 MB (half the suph lines) -> cache-resident.
__global__ __launch_bounds__(256, 4) void conv1_half_kernel(const int2* __restrict__ csr,
                                                            const int* __restrict__ row_start,
                                                            const ushort* __restrict__ suph,
                                                            const float* __restrict__ b1,
                                                            const float* __restrict__ w2t,
                                                            float* __restrict__ c2,
                                                            int N, int half_idx) {
    __shared__ float hrow[4][128];        // per-wave half-row, 2 KB
    const int wave = threadIdx.x >> 6;
    const int lane = threadIdx.x & 63;
    const int g    = lane >> 4;           // 0..3: edge slot within quad
    const int fl   = lane & 15;           // feat sub-block
    const int n = blockIdx.x * 4 + wave;
    if (n >= N) return;
    const int start = row_start[n], end = row_start[n + 1];
    const size_t foff = (size_t)half_idx * 128 + fl * 8;   // fp16 elements

    float acc[8] = {};
    for (int c0 = start; c0 < end; c0 += 64) {
        int clen = min(64, end - c0);
        int2 eL = (lane < clen) ? csr[c0 + lane] : make_int2(0, 0);
        int nq  = (clen + 3) >> 2;
        int nq8 = (nq + 7) & ~7;          // 8 or 16
        for (int t = 0; t < nq8; t += 8) {
            float wv[8];
            uint4 v[8];
            #pragma unroll
            for (int u = 0; u < 8; ++u) {
                int idx = 4 * (t + u) + g;            // <= 63 by construction
                int sidx = __shfl(eL.x, idx, 64);
                wv[u]    = __int_as_float(__shfl(eL.y, idx, 64));
                v[u] = *reinterpret_cast<const uint4*>(&suph[(size_t)sidx * NHID + foff]);
            }
            #pragma unroll
            for (int u = 0; u < 8; ++u) {
                acc[0] += wv[u] * hlo(v[u].x);
                acc[1] += wv[u] * hhi(v[u].x);
                acc[2] += wv[u] * hlo(v[u].y);
                acc[3] += wv[u] * hhi(v[u].y);
                acc[4] += wv[u] * hlo(v[u].z);
                acc[5] += wv[u] * hhi(v[u].z);
                acc[6] += wv[u] * hlo(v[u].w);
                acc[7] += wv[u] * hhi(v[u].w);
            }
        }
    }
    // reduce the 4 edge-groups (lanes fl, fl+16, fl+32, fl+48 hold same feats)
    #pragma unroll
    for (int i = 0; i < 8; ++i) {
        acc[i] += __shfl_xor(acc[i], 16, 64);
        acc[i] += __shfl_xor(acc[i], 32, 64);
    }
    if (lane < 16) {
        float4 ba = *reinterpret_cast<const float4*>(&b1[half_idx * 128 + fl * 8]);
        float4 bb = *reinterpret_cast<const float4*>(&b1[half_idx * 128 + fl * 8 + 4]);
        *reinterpret_cast<float4*>(&hrow[wave][fl * 8]) =
            make_float4(fmaxf(acc[0] + ba.x, 0.f), fmaxf(acc[1] + ba.y, 0.f),
                        fmaxf(acc[2] + ba.z, 0.f), fmaxf(acc[3] + ba.w, 0.f));
        *reinterpret_cast<float4*>(&hrow[wave][fl * 8 + 4]) =
            make_float4(fmaxf(acc[4] + bb.x, 0.f), fmaxf(acc[5] + bb.y, 0.f),
                        fmaxf(acc[6] + bb.z, 0.f), fmaxf(acc[7] + bb.w, 0.f));
    }
    // wave-local epilogue over this 128-feat half
    if (lane < NCLASS) {
        const float4* wp = reinterpret_cast<const float4*>(&w2t[(size_t)lane * NHID + half_idx * 128]);
        const float4* hp = reinterpret_cast<const float4*>(&hrow[wave][0]);
        float p = 0.f;
        #pragma unroll 8
        for (int k4 = 0; k4 < 32; ++k4) {
            float4 h4 = hp[k4];
            float4 w4 = wp[k4];
            p += h4.x * w4.x + h4.y * w4.y + h4.z * w4.z + h4.w * w4.w;
        }
        float* dp = &c2[(size_t)n * NCLASS + lane];
        if (half_idx == 0) *dp = p;
        else               *dp += p;
    }
}

// ---------------- conv2: out[n] = softmax( (A @ c2)[n] ) ----------------
// one wave per node; lanes 0..39 own classes; 16 edges in flight (r8 form).
__global__ __launch_bounds__(256, 4) void conv2_kernel(const int2* __restrict__ csr,
                                                       const int* __restrict__ row_start,
                                                       const float* __restrict__ c2,
                                                       float* __restrict__ out, int N) {
    int wave = threadIdx.x >> 6;
    int lane = threadIdx.x & 63;
    int n = blockIdx.x * 4 + wave;
    if (n >= N) return;
    int start = row_start[n], end = row_start[n + 1];
    bool act = lane < NCLASS;
    float acc = 0.f;
    int j = start;
    for (; j + 15 < end; j += 16) {
        int2 ee[16];
        #pragma unroll
        for (int u = 0; u < 16; ++u) ee[u] = csr[j + u];
        if (act) {
            float sv[16];
            #pragma unroll
            for (int u = 0; u < 16; ++u) sv[u] = c2[(size_t)ee[u].x * NCLASS + lane];
            #pragma unroll
            for (int u = 0; u < 16; ++u) acc += __int_as_float(ee[u].y) * sv[u];
        }
    }
    for (; j + 3 < end; j += 4) {
        int2 ee[4];
        #pragma unroll
        for (int u = 0; u < 4; ++u) ee[u] = csr[j + u];
        if (act) {
            float sv[4];
            #pragma unroll
            for (int u = 0; u < 4; ++u) sv[u] = c2[(size_t)ee[u].x * NCLASS + lane];
            #pragma unroll
            for (int u = 0; u < 4; ++u) acc += __int_as_float(ee[u].y) * sv[u];
        }
    }
    for (; j < end; ++j) {
        int2 e0 = csr[j];
        if (act) acc += __int_as_float(e0.y) * c2[(size_t)e0.x * NCLASS + lane];
    }
    float m = act ? acc : -INFINITY;
    #pragma unroll
    for (int off = 32; off > 0; off >>= 1) m = fmaxf(m, __shfl_xor(m, off, 64));
    float e = act ? expf(acc - m) : 0.f;
    float s = e;
    #pragma unroll
    for (int off = 32; off > 0; off >>= 1) s += __shfl_xor(s, off, 64);
    if (act) out[(size_t)n * NCLASS + lane] = e / s;
}

extern "C" void kernel_launch(void* const* d_in, const int* in_sizes, int n_in,
                              void* d_out, int out_size, void* d_ws, size_t ws_size,
                              hipStream_t stream) {
    const float* x  = (const float*)d_in[0];
    const int*   ei = (const int*)d_in[1];
    const float* ew = (const float*)d_in[2];
    const float* W1 = (const float*)d_in[3];
    const float* b1 = (const float*)d_in[4];
    const float* W2 = (const float*)d_in[5];
    float* out = (float*)d_out;

    const int M = in_sizes[0] / NFEAT;       // 100000
    const int E = in_sizes[1] / 2;           // 3200000
    const int* src = ei;
    const int* dst = ei + E;

    // workspace layout (~94 MB)
    char* ws = (char*)d_ws;
    ushort* suph    = (ushort*)ws;                                  // M*256 fp16 = 51.2 MB
    float*  c2      = (float*)(suph + (size_t)M * NHID);            // M*40 f32   = 16 MB
    int2*   csr     = (int2*)(c2 + (size_t)M * NCLASS);             // E int2     = 25.6 MB
    int*    deg     = (int*)(csr + E);                              // M
    int*    row_start = deg + M;                                    // M+1
    int*    cursor  = row_start + (M + 1);                          // M
    int*    bsums   = cursor + M;                                   // 128
    float*  w2t     = (float*)(bsums + 128);                        // 40*256 f32
    ushort* w1t     = (ushort*)(w2t + NCLASS * NHID);               // 256*512 fp16

    const int nscan = (M + SCAN_CHUNK - 1) / SCAN_CHUNK;

    // ---- converts + CSR build ----
    convert_w1t_kernel<<<NFEAT, 256, 0, stream>>>(W1, w1t);
    transpose_w2_kernel<<<1, 256, 0, stream>>>(W2, w2t);

    hipMemsetAsync(deg, 0, (size_t)M * 4, stream);
    hist_kernel<<<(E / 2 + 255) / 256, 256, 0, stream>>>(dst, deg, E / 2);
    scan1_kernel<<<nscan, 256, 0, stream>>>(deg, row_start, bsums, M);
    scan2_kernel<<<1, 128, 0, stream>>>(bsums, nscan);
    scan3_kernel<<<nscan, 256, 0, stream>>>(row_start, cursor, bsums, M, E);
    scatter_kernel<<<(E + 255) / 256, 256, 0, stream>>>(src, dst, ew, cursor, csr, E);

    // ---- dense + sparse pipeline ----
    dim3 g1((M + GM_BM - 1) / GM_BM, NHID / GM_BM);
    gemm1_mfma_kernel<<<g1, 256, 0, stream>>>(x, w1t, suph, M);

    conv1_half_kernel<<<(M + 3) / 4, 256, 0, stream>>>(csr, row_start, suph, b1, w2t, c2, M, 0);
    conv1_half_kernel<<<(M + 3) / 4, 256, 0, stream>>>(csr, row_start, suph, b1, w2t, c2, M, 1);
    conv2_kernel<<<(M + 3) / 4, 256, 0, stream>>>(csr, row_start, c2, out, M);
}

// Round 14
// 1044.289 us; speedup vs baseline: 1.1736x; 1.1030x over previous
//
#include <hip/hip_runtime.h>
#include <hip/hip_bf16.h>
#include <math.h>

// GCN forward: softmax( A * relu(A*(x@W1)+b1) @ W2 )
// N=100000 nodes, E=3.2M edges, F 512->256->40.
// CSR (dst-sorted) -> gather SpMM. support1 in FP16 (51 MB).
// conv1: wave-per-node single-pass gather -- at the measured L2-fill ceiling
// (~1.2 TB/s scattered 64B lines; r6-r13: ILP/occupancy/working-set splits all
// neutral). conv2: f32 c2, 40 lanes, 16-deep. gemm1: r7 128x128 MFMA form.
// CSR build: rank-from-hist (atomicAdd return) -> scatter with ZERO atomics.

#define NFEAT 512
#define NHID  256
#define NCLASS 40

typedef _Float16 f16x8 __attribute__((ext_vector_type(8)));
typedef float    f32x4 __attribute__((ext_vector_type(4)));

static __device__ __forceinline__ ushort f2h(float f) {
    _Float16 h = (_Float16)f;            // RNE
    ushort u; __builtin_memcpy(&u, &h, 2);
    return u;
}
static __device__ __forceinline__ float h2f(ushort u) {
    _Float16 h; __builtin_memcpy(&h, &u, 2);
    return (float)h;
}
static __device__ __forceinline__ float hlo(unsigned u) { return h2f((ushort)(u & 0xffff)); }
static __device__ __forceinline__ float hhi(unsigned u) { return h2f((ushort)(u >> 16)); }

static __device__ __forceinline__ uint4 pack8(float4 lo, float4 hi) {
    uint4 o;
    o.x = (unsigned)f2h(lo.x) | ((unsigned)f2h(lo.y) << 16);
    o.y = (unsigned)f2h(lo.z) | ((unsigned)f2h(lo.w) << 16);
    o.z = (unsigned)f2h(hi.x) | ((unsigned)f2h(hi.y) << 16);
    o.w = (unsigned)f2h(hi.z) | ((unsigned)f2h(hi.w) << 16);
    return o;
}

// ---------------- W1 -> W1T fp16  ([512][256] -> [256][512]) ----------------
__global__ __launch_bounds__(256) void convert_w1t_kernel(const float* __restrict__ W1,
                                                          ushort* __restrict__ w1t) {
    int k = blockIdx.x;      // 0..511
    int n = threadIdx.x;     // 0..255
    w1t[(size_t)n * NFEAT + k] = f2h(W1[(size_t)k * NHID + n]);
}

// ---------------- W2 transpose: W2T[40][256] <- W2[256][40] (f32) ----------------
__global__ __launch_bounds__(256) void transpose_w2_kernel(const float* __restrict__ W2,
                                                           float* __restrict__ W2T) {
    for (int i = threadIdx.x; i < NHID * NCLASS; i += 256) {
        int k = i / NCLASS, j = i - k * NCLASS;
        W2T[(size_t)j * NHID + k] = W2[i];
    }
}

// ---------------- gemm1 (MFMA fp16, r7 form): suph = fp16( x @ W1 ) ----------
#define GM_BM 128
#define GM_BK 32

__global__ __launch_bounds__(256) void gemm1_mfma_kernel(const float* __restrict__ A,
                                                         const ushort* __restrict__ Bt,
                                                         ushort* __restrict__ Ch,
                                                         int M) {
    __shared__ ushort As[GM_BM * GM_BK];   // 8 KB, XOR-swizzled 16B slots
    __shared__ ushort Bs[GM_BM * GM_BK];   // 8 KB
    const int tid = threadIdx.x;
    const int wid = tid >> 6, lane = tid & 63;
    const int row0 = blockIdx.x * GM_BM;
    const int col0 = blockIdx.y * GM_BM;   // 0 or 128 (N=256)
    const int wr = (wid >> 1) * 64;
    const int wc = (wid & 1) * 64;
    const int l15 = lane & 15;
    const int lq  = lane >> 4;             // k-chunk 0..3

    const int sr = tid >> 2;               // staging row 0..63
    const int sc = tid & 3;                // staging 16B slot (8 fp16 / 32B f32)

    f32x4 acc[4][4] = {};

    for (int k0 = 0; k0 < NFEAT; k0 += GM_BK) {
        {
            int r0g = row0 + sr;
            int r1g = row0 + sr + 64;
            uint4 a0 = make_uint4(0, 0, 0, 0), a1 = make_uint4(0, 0, 0, 0);
            if (r0g < M) {
                const float4* p = reinterpret_cast<const float4*>(&A[(size_t)r0g * NFEAT + k0 + sc * 8]);
                a0 = pack8(p[0], p[1]);
            }
            if (r1g < M) {
                const float4* p = reinterpret_cast<const float4*>(&A[(size_t)r1g * NFEAT + k0 + sc * 8]);
                a1 = pack8(p[0], p[1]);
            }
            int sw0 = sc ^ ((sr ^ (sr >> 2)) & 3);
            int sw1 = sc ^ (((sr + 64) ^ ((sr + 64) >> 2)) & 3);
            *reinterpret_cast<uint4*>(&As[sr * GM_BK + sw0 * 8]) = a0;
            *reinterpret_cast<uint4*>(&As[(sr + 64) * GM_BK + sw1 * 8]) = a1;
            uint4 b0 = *reinterpret_cast<const uint4*>(&Bt[(size_t)(col0 + sr) * NFEAT + k0 + sc * 8]);
            uint4 b1v = *reinterpret_cast<const uint4*>(&Bt[(size_t)(col0 + sr + 64) * NFEAT + k0 + sc * 8]);
            *reinterpret_cast<uint4*>(&Bs[sr * GM_BK + sw0 * 8]) = b0;
            *reinterpret_cast<uint4*>(&Bs[(sr + 64) * GM_BK + sw1 * 8]) = b1v;
        }
        __syncthreads();
        f16x8 af[4], bfr[4];
        #pragma unroll
        for (int mi = 0; mi < 4; ++mi) {
            int r = wr + mi * 16 + l15;
            int sw = lq ^ ((r ^ (r >> 2)) & 3);
            af[mi] = *reinterpret_cast<const f16x8*>(&As[r * GM_BK + sw * 8]);
        }
        #pragma unroll
        for (int ni = 0; ni < 4; ++ni) {
            int c = wc + ni * 16 + l15;
            int sw = lq ^ ((c ^ (c >> 2)) & 3);
            bfr[ni] = *reinterpret_cast<const f16x8*>(&Bs[c * GM_BK + sw * 8]);
        }
        #pragma unroll
        for (int mi = 0; mi < 4; ++mi)
            #pragma unroll
            for (int ni = 0; ni < 4; ++ni)
                acc[mi][ni] = __builtin_amdgcn_mfma_f32_16x16x32_f16(af[mi], bfr[ni], acc[mi][ni], 0, 0, 0);
        __syncthreads();
    }
    // C/D layout: col = lane&15, row = (lane>>4)*4 + reg
    #pragma unroll
    for (int mi = 0; mi < 4; ++mi) {
        #pragma unroll
        for (int j = 0; j < 4; ++j) {
            int gr = row0 + wr + mi * 16 + lq * 4 + j;
            if (gr < M) {
                #pragma unroll
                for (int ni = 0; ni < 4; ++ni) {
                    Ch[(size_t)gr * NHID + col0 + wc + ni * 16 + l15] = f2h(acc[mi][ni][j]);
                }
            }
        }
    }
}

// ---------------- CSR build (rank-based, scatter has no atomics) ----------------
__global__ __launch_bounds__(256) void hist_kernel(const int* __restrict__ dst,
                                                   int* __restrict__ deg,
                                                   int* __restrict__ rank, int E2) {
    int i = blockIdx.x * 256 + threadIdx.x;
    if (i < E2) {
        int2 d2 = reinterpret_cast<const int2*>(dst)[i];
        int r0 = atomicAdd(&deg[d2.x], 1);
        int r1 = atomicAdd(&deg[d2.y], 1);
        reinterpret_cast<int2*>(rank)[i] = make_int2(r0, r1);
    }
}

#define SCAN_CHUNK 1024
__global__ __launch_bounds__(256) void scan1_kernel(const int* __restrict__ deg,
                                                    int* __restrict__ part,
                                                    int* __restrict__ bsums, int N) {
    __shared__ int s[256];
    int b = blockIdx.x, t = threadIdx.x;
    int i0 = b * SCAN_CHUNK + t * 4;
    int d[4];
    #pragma unroll
    for (int u = 0; u < 4; ++u) d[u] = (i0 + u < N) ? deg[i0 + u] : 0;
    int loc = d[0] + d[1] + d[2] + d[3];
    s[t] = loc;
    __syncthreads();
    for (int off = 1; off < 256; off <<= 1) {
        int v = (t >= off) ? s[t - off] : 0;
        __syncthreads();
        s[t] += v;
        __syncthreads();
    }
    int run = s[t] - loc;
    #pragma unroll
    for (int u = 0; u < 4; ++u) {
        if (i0 + u < N) part[i0 + u] = run;
        run += d[u];
    }
    if (t == 255) bsums[b] = s[255];
}

__global__ __launch_bounds__(128) void scan2_kernel(int* __restrict__ bsums, int nb) {
    __shared__ int s[128];
    int t = threadIdx.x;
    int v = (t < nb) ? bsums[t] : 0;
    s[t] = v;
    __syncthreads();
    for (int off = 1; off < 128; off <<= 1) {
        int x = (t >= off) ? s[t - off] : 0;
        __syncthreads();
        s[t] += x;
        __syncthreads();
    }
    if (t < nb) bsums[t] = s[t] - v;
}

__global__ __launch_bounds__(256) void scan3_kernel(int* __restrict__ row_start,
                                                    const int* __restrict__ bsums,
                                                    int N, int E) {
    int b = blockIdx.x, t = threadIdx.x;
    int i0 = b * SCAN_CHUNK + t * 4;
    int add = bsums[b];
    #pragma unroll
    for (int u = 0; u < 4; ++u)
        if (i0 + u < N) row_start[i0 + u] += add;
    if (b == 0 && t == 0) row_start[N] = E;
}

__global__ __launch_bounds__(256) void scatter_kernel(const int* __restrict__ src,
                                                      const int* __restrict__ dst,
                                                      const float* __restrict__ w,
                                                      const int* __restrict__ row_start,
                                                      const int* __restrict__ rank,
                                                      int2* __restrict__ csr, int E) {
    int e = blockIdx.x * 256 + threadIdx.x;
    if (e >= E) return;
    int d = dst[e];
    int pos = row_start[d] + rank[e];
    csr[pos] = make_int2(src[e], __float_as_int(w[e]));
}

// ---------------- conv1: c2[n] = relu( (A @ suph)[n] + b1 ) @ W2 ----------------
// ONE WAVE per node (proven 609us form, at gather ceiling -- do not touch).
__global__ __launch_bounds__(256, 4) void conv1_kernel(const int2* __restrict__ csr,
                                                       const int* __restrict__ row_start,
                                                       const ushort* __restrict__ suph,
                                                       const float* __restrict__ b1,
                                                       const float* __restrict__ w2t,
                                                       float* __restrict__ c2, int N) {
    __shared__ float hrow[4][NHID];       // per-wave slice, 4 KB
    const int wave = threadIdx.x >> 6;
    const int lane = threadIdx.x & 63;
    const int half = lane >> 5;
    const int fl   = lane & 31;
    const int n = blockIdx.x * 4 + wave;
    if (n >= N) return;
    const int start = row_start[n], end = row_start[n + 1];

    float acc[8] = {};
    for (int c0 = start; c0 < end; c0 += 64) {
        int clen = min(64, end - c0);
        int2 eL = (lane < clen) ? csr[c0 + lane] : make_int2(0, 0);
        int npairs  = (clen + 1) >> 1;
        int npair8  = (npairs + 7) & ~7;
        for (int t = 0; t < npair8; t += 8) {
            float wv[8];
            uint4 v[8];
            #pragma unroll
            for (int u = 0; u < 8; ++u) {
                int idx = 2 * (t + u) + half;    // <= 63 by construction
                int sidx = __shfl(eL.x, idx, 64);
                wv[u]    = __int_as_float(__shfl(eL.y, idx, 64));
                v[u] = *reinterpret_cast<const uint4*>(&suph[(size_t)sidx * NHID + fl * 8]);
            }
            #pragma unroll
            for (int u = 0; u < 8; ++u) {
                acc[0] += wv[u] * hlo(v[u].x);
                acc[1] += wv[u] * hhi(v[u].x);
                acc[2] += wv[u] * hlo(v[u].y);
                acc[3] += wv[u] * hhi(v[u].y);
                acc[4] += wv[u] * hlo(v[u].z);
                acc[5] += wv[u] * hhi(v[u].z);
                acc[6] += wv[u] * hlo(v[u].w);
                acc[7] += wv[u] * hhi(v[u].w);
            }
        }
    }
    #pragma unroll
    for (int i = 0; i < 8; ++i) acc[i] += __shfl_xor(acc[i], 32, 64);
    if (half == 0) {
        float4 ba = *reinterpret_cast<const float4*>(&b1[fl * 8]);
        float4 bb = *reinterpret_cast<const float4*>(&b1[fl * 8 + 4]);
        *reinterpret_cast<float4*>(&hrow[wave][fl * 8]) =
            make_float4(fmaxf(acc[0] + ba.x, 0.f), fmaxf(acc[1] + ba.y, 0.f),
                        fmaxf(acc[2] + ba.z, 0.f), fmaxf(acc[3] + ba.w, 0.f));
        *reinterpret_cast<float4*>(&hrow[wave][fl * 8 + 4]) =
            make_float4(fmaxf(acc[4] + bb.x, 0.f), fmaxf(acc[5] + bb.y, 0.f),
                        fmaxf(acc[6] + bb.z, 0.f), fmaxf(acc[7] + bb.w, 0.f));
    }
    // wave-local epilogue (same wave wrote hrow[wave])
    if (lane < NCLASS) {
        const float4* wp = reinterpret_cast<const float4*>(&w2t[(size_t)lane * NHID]);
        const float4* hp = reinterpret_cast<const float4*>(&hrow[wave][0]);
        float p = 0.f;
        #pragma unroll 8
        for (int k4 = 0; k4 < 64; ++k4) {
            float4 h4 = hp[k4];
            float4 w4 = wp[k4];
            p += h4.x * w4.x + h4.y * w4.y + h4.z * w4.z + h4.w * w4.w;
        }
        c2[(size_t)n * NCLASS + lane] = p;
    }
}

// ---------------- conv2: out[n] = softmax( (A @ c2)[n] ) ----------------
// one wave per node; lanes 0..39 own classes; 16 edges in flight.
__global__ __launch_bounds__(256, 4) void conv2_kernel(const int2* __restrict__ csr,
                                                       const int* __restrict__ row_start,
                                                       const float* __restrict__ c2,
                                                       float* __restrict__ out, int N) {
    int wave = threadIdx.x >> 6;
    int lane = threadIdx.x & 63;
    int n = blockIdx.x * 4 + wave;
    if (n >= N) return;
    int start = row_start[n], end = row_start[n + 1];
    bool act = lane < NCLASS;
    float acc = 0.f;
    int j = start;
    for (; j + 15 < end; j += 16) {
        int2 ee[16];
        #pragma unroll
        for (int u = 0; u < 16; ++u) ee[u] = csr[j + u];
        if (act) {
            float sv[16];
            #pragma unroll
            for (int u = 0; u < 16; ++u) sv[u] = c2[(size_t)ee[u].x * NCLASS + lane];
            #pragma unroll
            for (int u = 0; u < 16; ++u) acc += __int_as_float(ee[u].y) * sv[u];
        }
    }
    for (; j + 3 < end; j += 4) {
        int2 ee[4];
        #pragma unroll
        for (int u = 0; u < 4; ++u) ee[u] = csr[j + u];
        if (act) {
            float sv[4];
            #pragma unroll
            for (int u = 0; u < 4; ++u) sv[u] = c2[(size_t)ee[u].x * NCLASS + lane];
            #pragma unroll
            for (int u = 0; u < 4; ++u) acc += __int_as_float(ee[u].y) * sv[u];
        }
    }
    for (; j < end; ++j) {
        int2 e0 = csr[j];
        if (act) acc += __int_as_float(e0.y) * c2[(size_t)e0.x * NCLASS + lane];
    }
    float m = act ? acc : -INFINITY;
    #pragma unroll
    for (int off = 32; off > 0; off >>= 1) m = fmaxf(m, __shfl_xor(m, off, 64));
    float e = act ? expf(acc - m) : 0.f;
    float s = e;
    #pragma unroll
    for (int off = 32; off > 0; off >>= 1) s += __shfl_xor(s, off, 64);
    if (act) out[(size_t)n * NCLASS + lane] = e / s;
}

extern "C" void kernel_launch(void* const* d_in, const int* in_sizes, int n_in,
                              void* d_out, int out_size, void* d_ws, size_t ws_size,
                              hipStream_t stream) {
    const float* x  = (const float*)d_in[0];
    const int*   ei = (const int*)d_in[1];
    const float* ew = (const float*)d_in[2];
    const float* W1 = (const float*)d_in[3];
    const float* b1 = (const float*)d_in[4];
    const float* W2 = (const float*)d_in[5];
    float* out = (float*)d_out;

    const int M = in_sizes[0] / NFEAT;       // 100000
    const int E = in_sizes[1] / 2;           // 3200000
    const int* src = ei;
    const int* dst = ei + E;

    // workspace layout (~107 MB)
    char* ws = (char*)d_ws;
    ushort* suph    = (ushort*)ws;                                  // M*256 fp16 = 51.2 MB
    float*  c2      = (float*)(suph + (size_t)M * NHID);            // M*40 f32   = 16 MB
    int2*   csr     = (int2*)(c2 + (size_t)M * NCLASS);             // E int2     = 25.6 MB
    int*    rank    = (int*)(csr + E);                              // E int      = 12.8 MB
    int*    deg     = rank + E;                                     // M
    int*    row_start = deg + M;                                    // M+1
    int*    bsums   = row_start + (M + 1);                          // 128
    float*  w2t     = (float*)(bsums + 128);                        // 40*256 f32
    ushort* w1t     = (ushort*)(w2t + NCLASS * NHID);               // 256*512 fp16

    const int nscan = (M + SCAN_CHUNK - 1) / SCAN_CHUNK;

    // ---- converts + CSR build ----
    convert_w1t_kernel<<<NFEAT, 256, 0, stream>>>(W1, w1t);
    transpose_w2_kernel<<<1, 256, 0, stream>>>(W2, w2t);

    hipMemsetAsync(deg, 0, (size_t)M * 4, stream);
    hist_kernel<<<(E / 2 + 255) / 256, 256, 0, stream>>>(dst, deg, rank, E / 2);
    scan1_kernel<<<nscan, 256, 0, stream>>>(deg, row_start, bsums, M);
    scan2_kernel<<<1, 128, 0, stream>>>(bsums, nscan);
    scan3_kernel<<<nscan, 256, 0, stream>>>(row_start, bsums, M, E);
    scatter_kernel<<<(E + 255) / 256, 256, 0, stream>>>(src, dst, ew, row_start, rank, csr, E);

    // ---- dense + sparse pipeline ----
    dim3 g1((M + GM_BM - 1) / GM_BM, NHID / GM_BM);
    gemm1_mfma_kernel<<<g1, 256, 0, stream>>>(x, w1t, suph, M);

    conv1_kernel<<<(M + 3) / 4, 256, 0, stream>>>(csr, row_start, suph, b1, w2t, c2, M);
    conv2_kernel<<<(M + 3) / 4, 256, 0, stream>>>(csr, row_start, c2, out, M);
}